// Round 5
// baseline (46.865 us; speedup 1.0000x reference)
//
#include <hip/hip_runtime.h>

#define B_ 16
#define U_ 500
#define S_ 256
#define H_ 128
#define UTILE 32
#define NWAVES 8
#define TPB (NWAVES * 64)   // 512 threads, 8 waves, 4 u-rows per wave

__global__ __launch_bounds__(TPB, 2) void attn_kernel(
    const float* __restrict__ user,     // (B,U,4)
    const float* __restrict__ server,   // (B,S,6)
    const int*   __restrict__ masks,    // (B,U,S) int32 0/1 OR packed bytes (auto-detected)
    const float* __restrict__ Wu,       // (3,H)
    const float* __restrict__ bu,       // (H)
    const float* __restrict__ Ws,       // (7,H)  (row 6 multiplies the zero 'active' col -> unused)
    const float* __restrict__ bs,       // (H)
    const float* __restrict__ W1,       // (H,H)
    const float* __restrict__ W2,       // (H,H)
    const float* __restrict__ vt,       // (H)
    float* __restrict__ out)            // (B,U,S) fp32
{
  __shared__ float E[H_][S_];           // 128 KB, transposed [h][s], holds exp(2*enc)
  __shared__ float M1s[6 * H_];         // Ws@W1 (rows 0..5)
  __shared__ float M2s[3 * H_];         // Wu@W2
  __shared__ float c1s[H_];             // bs@W1
  __shared__ float c2s[H_];             // bu@W2
  __shared__ float vts[H_];
  __shared__ float decs[NWAVES][4][H_]; // exp(2*dec), 4 u-rows per wave, 16 KB
  __shared__ float vsum_s;

  const int tid = threadIdx.x;
  const int bid = blockIdx.x;
  const int b   = bid >> 4;
  const int u0  = (bid & 15) * UTILE;

  // ---- phase 0: fused weight products (redundant per block, negligible) ----
  {
    const int h = tid & (H_ - 1);
    for (int job = tid >> 7; job < 11; job += 4) {   // 4 groups of 128 threads
      const float* Lv; const float* Rm; float* dst;
      if (job < 6)       { Lv = Ws + job * H_;       Rm = W1; dst = M1s + job * H_; }
      else if (job == 6) { Lv = bs;                  Rm = W1; dst = c1s; }
      else if (job < 10) { Lv = Wu + (job - 7) * H_; Rm = W2; dst = M2s + (job - 7) * H_; }
      else               { Lv = bu;                  Rm = W2; dst = c2s; }
      float acc = 0.f;
      for (int j = 0; j < H_; ++j) acc = fmaf(Lv[j], Rm[j * H_ + h], acc);
      dst[h] = acc;
    }
    if (tid < H_) vts[tid] = vt[tid];
    if (tid < 64) {                       // vsum = sum(vt), from global (no LDS dep)
      float v = vt[tid] + vt[tid + 64];
      #pragma unroll
      for (int off = 32; off > 0; off >>= 1) v += __shfl_xor(v, off, 64);
      if (tid == 0) vsum_s = v;
    }
  }

  // ---- mask dtype detection: int32 masks are strictly 0/1; packed bools make words >1 ----
  int lflag;
  {
    int4 mw = *reinterpret_cast<const int4*>(masks + tid * 4);   // first 2048 words, in-bounds either way
    lflag = ((unsigned)mw.x > 1u) | ((unsigned)mw.y > 1u) |
            ((unsigned)mw.z > 1u) | ((unsigned)mw.w > 1u);
  }
  const int bytemode = __syncthreads_or(lflag);   // barrier also publishes phase-0 LDS

  // ---- phase 1: stage E[h][s] = exp(2*(c1[h] + sum_k server[b,s,k]*M1[k][h])) ----
  {
    const int s  = tid & (S_ - 1);
    const int h0 = tid >> 8;   // 0..1, wave-uniform
    const float2* sv = reinterpret_cast<const float2*>(server + ((size_t)b * S_ + s) * 6);
    const float2 p0 = sv[0], p1 = sv[1], p2 = sv[2];
    for (int h = h0; h < H_; h += 2) {
      float a = c1s[h];
      a = fmaf(p0.x, M1s[0 * H_ + h], a);
      a = fmaf(p0.y, M1s[1 * H_ + h], a);
      a = fmaf(p1.x, M1s[2 * H_ + h], a);
      a = fmaf(p1.y, M1s[3 * H_ + h], a);
      a = fmaf(p2.x, M1s[4 * H_ + h], a);
      a = fmaf(p2.y, M1s[5 * H_ + h], a);
      E[h][s] = __expf(fminf(fmaxf(a + a, -60.f), 60.f));
    }
  }

  const int w    = tid >> 6;
  const int lane = tid & 63;
  const int ub   = u0 + 4 * w;          // this wave's 4 u-rows: ub..ub+3

  // ---- dec rows for the wave's 4 u's: D = exp(2*dec). Same-wave LDS slot. ----
  {
    #pragma unroll
    for (int r = 0; r < 4; ++r) {
      const int ucr = min(ub + r, U_ - 1);
      const float* uv = user + ((size_t)b * U_ + ucr) * 4;
      const float g0 = uv[0], g1 = uv[1], g2 = uv[2];
      #pragma unroll
      for (int hh = 0; hh < 2; ++hh) {
        const int h = lane + hh * 64;
        float a = c2s[h];
        a = fmaf(g0, M2s[0 * H_ + h], a);
        a = fmaf(g1, M2s[1 * H_ + h], a);
        a = fmaf(g2, M2s[2 * H_ + h], a);
        decs[w][r][h] = __expf(fminf(fmaxf(a + a, -60.f), 60.f));
      }
    }
  }
  __syncthreads();   // publishes E (decs is same-wave, also covered)

  // ---- issue mask loads early to hide HBM latency under the h4 loop ----
  size_t ridx[4];
  int m[4][4];
  #pragma unroll
  for (int r = 0; r < 4; ++r)
    ridx[r] = ((size_t)b * U_ + min(ub + r, U_ - 1)) * S_ + (size_t)lane * 4;
  if (!bytemode) {
    #pragma unroll
    for (int r = 0; r < 4; ++r) {
      int4 mm = *reinterpret_cast<const int4*>(masks + ridx[r]);
      m[r][0] = mm.x; m[r][1] = mm.y; m[r][2] = mm.z; m[r][3] = mm.w;
    }
  } else {
    const unsigned char* mb = reinterpret_cast<const unsigned char*>(masks);
    #pragma unroll
    for (int r = 0; r < 4; ++r) {
      uchar4 mm = *reinterpret_cast<const uchar4*>(mb + ridx[r]);
      m[r][0] = mm.x; m[r][1] = mm.y; m[r][2] = mm.z; m[r][3] = mm.w;
    }
  }

  // ---- main accumulation: lane l owns s = 4l..4l+3 for FOUR u-rows per E pass ----
  // Each float4 E-read now feeds 4 quads (vs 2 in the previous best): LDS instrs
  // per CU-iteration drop 112 -> 72 and E b128 reads halve, at constant VALU.
  // acc = sum_h v_h / (E_h*D_h + 1), 4 h at a time with ONE rcp:
  //   sum v_i/t_i = ((v0 t1 + v1 t0) t2 t3 + (v2 t3 + v3 t2) t0 t1) / (t0 t1 t2 t3)
  float a0_0 = 0.f, a0_1 = 0.f, a0_2 = 0.f, a0_3 = 0.f;
  float a1_0 = 0.f, a1_1 = 0.f, a1_2 = 0.f, a1_3 = 0.f;
  float a2_0 = 0.f, a2_1 = 0.f, a2_2 = 0.f, a2_3 = 0.f;
  float a3_0 = 0.f, a3_1 = 0.f, a3_2 = 0.f, a3_3 = 0.f;

  auto quad = [](const float4& vv, float ea, float eb, float ec, float ed,
                 const float4& d, float& acc) {
    float t0 = fmaf(ea, d.x, 1.0f);
    float t1 = fmaf(eb, d.y, 1.0f);
    float t2 = fmaf(ec, d.z, 1.0f);
    float t3 = fmaf(ed, d.w, 1.0f);
    float t01 = t0 * t1;
    float t23 = t2 * t3;
    float n01 = fmaf(vv.x, t1, vv.y * t0);
    float n23 = fmaf(vv.z, t3, vv.w * t2);
    float den = t01 * t23;
    float num = fmaf(n01, t23, n23 * t01);
    acc = fmaf(num, __builtin_amdgcn_rcpf(den), acc);
  };

  #pragma unroll 2
  for (int h4 = 0; h4 < H_ / 4; ++h4) {
    const int hh = h4 * 4;
    const float4 e0 = *reinterpret_cast<const float4*>(&E[hh + 0][lane * 4]);
    const float4 e1 = *reinterpret_cast<const float4*>(&E[hh + 1][lane * 4]);
    const float4 e2 = *reinterpret_cast<const float4*>(&E[hh + 2][lane * 4]);
    const float4 e3 = *reinterpret_cast<const float4*>(&E[hh + 3][lane * 4]);
    const float4 d0 = *reinterpret_cast<const float4*>(&decs[w][0][hh]);   // LDS broadcast
    const float4 d1 = *reinterpret_cast<const float4*>(&decs[w][1][hh]);   // LDS broadcast
    const float4 d2 = *reinterpret_cast<const float4*>(&decs[w][2][hh]);   // LDS broadcast
    const float4 d3 = *reinterpret_cast<const float4*>(&decs[w][3][hh]);   // LDS broadcast
    const float4 v4 = *reinterpret_cast<const float4*>(&vts[hh]);          // LDS broadcast

    quad(v4, e0.x, e1.x, e2.x, e3.x, d0, a0_0);
    quad(v4, e0.y, e1.y, e2.y, e3.y, d0, a0_1);
    quad(v4, e0.z, e1.z, e2.z, e3.z, d0, a0_2);
    quad(v4, e0.w, e1.w, e2.w, e3.w, d0, a0_3);
    quad(v4, e0.x, e1.x, e2.x, e3.x, d1, a1_0);
    quad(v4, e0.y, e1.y, e2.y, e3.y, d1, a1_1);
    quad(v4, e0.z, e1.z, e2.z, e3.z, d1, a1_2);
    quad(v4, e0.w, e1.w, e2.w, e3.w, d1, a1_3);
    quad(v4, e0.x, e1.x, e2.x, e3.x, d2, a2_0);
    quad(v4, e0.y, e1.y, e2.y, e3.y, d2, a2_1);
    quad(v4, e0.z, e1.z, e2.z, e3.z, d2, a2_2);
    quad(v4, e0.w, e1.w, e2.w, e3.w, d2, a2_3);
    quad(v4, e0.x, e1.x, e2.x, e3.x, d3, a3_0);
    quad(v4, e0.y, e1.y, e2.y, e3.y, d3, a3_1);
    quad(v4, e0.z, e1.z, e2.z, e3.z, d3, a3_2);
    quad(v4, e0.w, e1.w, e2.w, e3.w, d3, a3_3);
  }

  // ---- mask + softmax + store (per-row validity; branch is wave-uniform) ----
  const float negs = -103.6163291847321f * 10.0f;   // log(1e-45) * EXPLORATION_C
  const float vs10 = vsum_s * 10.0f;
  #pragma unroll
  for (int r = 0; r < 4; ++r) {
    if (ub + r < U_) {
      const float b0 = (r == 0) ? a0_0 : (r == 1) ? a1_0 : (r == 2) ? a2_0 : a3_0;
      const float b1 = (r == 0) ? a0_1 : (r == 1) ? a1_1 : (r == 2) ? a2_1 : a3_1;
      const float b2 = (r == 0) ? a0_2 : (r == 1) ? a1_2 : (r == 2) ? a2_2 : a3_2;
      const float b3 = (r == 0) ? a0_3 : (r == 1) ? a1_3 : (r == 2) ? a2_3 : a3_3;
      float s0 = m[r][0] ? fmaf(-20.0f, b0, vs10) : negs;
      float s1 = m[r][1] ? fmaf(-20.0f, b1, vs10) : negs;
      float s2 = m[r][2] ? fmaf(-20.0f, b2, vs10) : negs;
      float s3 = m[r][3] ? fmaf(-20.0f, b3, vs10) : negs;
      float mx = fmaxf(fmaxf(s0, s1), fmaxf(s2, s3));
      #pragma unroll
      for (int off = 32; off > 0; off >>= 1) mx = fmaxf(mx, __shfl_xor(mx, off, 64));
      float p0 = __expf(s0 - mx);
      float p1 = __expf(s1 - mx);
      float p2 = __expf(s2 - mx);
      float p3 = __expf(s3 - mx);
      float sum = (p0 + p1) + (p2 + p3);
      #pragma unroll
      for (int off = 32; off > 0; off >>= 1) sum += __shfl_xor(sum, off, 64);
      const float inv = __builtin_amdgcn_rcpf(sum);
      float4 o;
      o.x = p0 * inv; o.y = p1 * inv; o.z = p2 * inv; o.w = p3 * inv;
      *reinterpret_cast<float4*>(out + ridx[r]) = o;
    }
  }
}

extern "C" void kernel_launch(void* const* d_in, const int* in_sizes, int n_in,
                              void* d_out, int out_size, void* d_ws, size_t ws_size,
                              hipStream_t stream) {
  const float* user   = (const float*)d_in[0];
  const float* server = (const float*)d_in[1];
  const int*   masks  = (const int*)d_in[2];
  const float* Wu = (const float*)d_in[3];
  const float* bu = (const float*)d_in[4];
  const float* Ws = (const float*)d_in[5];
  const float* bs = (const float*)d_in[6];
  const float* W1 = (const float*)d_in[7];
  const float* W2 = (const float*)d_in[8];
  const float* vt = (const float*)d_in[9];
  float* out = (float*)d_out;
  (void)in_sizes; (void)n_in; (void)out_size; (void)d_ws; (void)ws_size;

  attn_kernel<<<dim3(B_ * ((U_ + UTILE - 1) / UTILE)), dim3(TPB), 0, stream>>>(
      user, server, masks, Wu, bu, Ws, bs, W1, W2, vt, out);
}

// Round 7
// 44.856 us; speedup vs baseline: 1.0448x; 1.0448x over previous
//
#include <hip/hip_runtime.h>

#define B_ 16
#define U_ 500
#define S_ 256
#define H_ 128
#define UTILE 32
#define NWAVES 16
#define TPB (NWAVES * 64)

__global__ __launch_bounds__(TPB, 1) void attn_kernel(
    const float* __restrict__ user,     // (B,U,4)
    const float* __restrict__ server,   // (B,S,6)
    const int*   __restrict__ masks,    // (B,U,S) int32 0/1 OR packed bytes (auto-detected)
    const float* __restrict__ Wu,       // (3,H)
    const float* __restrict__ bu,       // (H)
    const float* __restrict__ Ws,       // (7,H)  (row 6 multiplies the zero 'active' col -> unused)
    const float* __restrict__ bs,       // (H)
    const float* __restrict__ W1,       // (H,H)
    const float* __restrict__ W2,       // (H,H)
    const float* __restrict__ vt,       // (H)
    float* __restrict__ out)            // (B,U,S) fp32
{
  // Transposed E: Et[s][h] = exp(2*enc), with XOR-quad swizzle on the h-quad
  // index (quad' = h4 ^ (s&7)) so same-column reads from scattered s rows
  // spread across 8 bank-phases. 128 KB.
  __shared__ float Et[S_][H_];
  __shared__ float M1s[6 * H_];        // 2*(Ws@W1) rows 0..5 (pre-doubled)
  __shared__ float M2s[3 * H_];        // 2*(Wu@W2)
  __shared__ float c1s[H_];            // 2*(bs@W1)
  __shared__ float c2s[H_];            // 2*(bu@W2)
  __shared__ float decs[NWAVES][2][H_];// exp(2*dec) per wave's two u-rows
  __shared__ unsigned char slist[NWAVES][512]; // survivor s-list (row A ranks, then row B)
  __shared__ float vsum_s;

  const int tid  = threadIdx.x;
  const int bid  = blockIdx.x;
  const int b    = bid >> 4;
  const int u0   = (bid & 15) * UTILE;
  const int w    = tid >> 6;
  const int lane = tid & 63;

  // ---- issue mask dtype probe early (consumed after phase 0, per-wave OR) ----
  int4 mw = *reinterpret_cast<const int4*>(masks + tid * 4);  // words 0..4095, in-bounds either way

  // ---- phase 0: fused weight products, PRE-DOUBLED (folds the 2x inside exp) ----
  {
    const int h = tid & (H_ - 1);
    for (int job = tid >> 7; job < 11; job += 8) {
      const float* Lv; const float* Rm; float* dst;
      if (job < 6)       { Lv = Ws + job * H_;       Rm = W1; dst = M1s + job * H_; }
      else if (job == 6) { Lv = bs;                  Rm = W1; dst = c1s; }
      else if (job < 10) { Lv = Wu + (job - 7) * H_; Rm = W2; dst = M2s + (job - 7) * H_; }
      else               { Lv = bu;                  Rm = W2; dst = c2s; }
      float acc = 0.f;
      for (int j = 0; j < H_; ++j) acc = fmaf(Lv[j], Rm[j * H_ + h], acc);
      dst[h] = acc + acc;              // pre-doubled
    }
    if (tid < 64) {                    // vsum = sum(vt) (NOT doubled)
      float v = vt[tid] + vt[tid + 64];
      #pragma unroll
      for (int off = 32; off > 0; off >>= 1) v += __shfl_xor(v, off, 64);
      if (tid == 0) vsum_s = v;
    }
  }
  __syncthreads();   // publish phase-0 weights

  // ---- mask dtype detection (wave-local OR; same 16KB probe window as before) ----
  const int lflag = ((unsigned)mw.x > 1u) | ((unsigned)mw.y > 1u) |
                    ((unsigned)mw.z > 1u) | ((unsigned)mw.w > 1u);
  const int bytemode = __any(lflag);

  const int uA  = u0 + 2 * w;          // both rows valid or both invalid (U_ even, u0 even)
  const int uAc = min(uA,     U_ - 1);
  const int uBc = min(uA + 1, U_ - 1);
  const size_t rowA = ((size_t)b * U_ + uAc) * S_;
  const size_t rowB = ((size_t)b * U_ + uBc) * S_;

  // ---- issue mask loads early; latency hides under phase-1 staging ----
  int m[2][4];
  if (uA < U_) {
    if (!bytemode) {
      int4 ma = *reinterpret_cast<const int4*>(masks + rowA + lane * 4);
      int4 mb = *reinterpret_cast<const int4*>(masks + rowB + lane * 4);
      m[0][0] = ma.x; m[0][1] = ma.y; m[0][2] = ma.z; m[0][3] = ma.w;
      m[1][0] = mb.x; m[1][1] = mb.y; m[1][2] = mb.z; m[1][3] = mb.w;
    } else {
      const unsigned char* mbp = reinterpret_cast<const unsigned char*>(masks);
      uchar4 ma = *reinterpret_cast<const uchar4*>(mbp + rowA + lane * 4);
      uchar4 mb = *reinterpret_cast<const uchar4*>(mbp + rowB + lane * 4);
      m[0][0] = ma.x; m[0][1] = ma.y; m[0][2] = ma.z; m[0][3] = ma.w;
      m[1][0] = mb.x; m[1][1] = mb.y; m[1][2] = mb.z; m[1][3] = mb.w;
    }
  }

  // ---- phase 1: stage Et[s][h] = exp(2*enc), transposed + swizzled ----
  {
    const int s  = tid & (S_ - 1);
    const int h0 = tid >> 8;           // 0..3: thread covers quads h0*8 .. h0*8+7
    const int P  = (s << 9) + ((s & 7) << 4);   // row base byte ^ swizzle field
    char* etb = (char*)Et;
    const float2* sv = reinterpret_cast<const float2*>(server + ((size_t)b * S_ + s) * 6);
    const float2 p0 = sv[0], p1 = sv[1], p2 = sv[2];
    #pragma unroll
    for (int g = 0; g < 8; ++g) {
      const int hq = h0 * 8 + g;
      const int hb = hq * 4;
      const float4 c  = *reinterpret_cast<const float4*>(&c1s[hb]);
      const float4 q0 = *reinterpret_cast<const float4*>(&M1s[0 * H_ + hb]);
      const float4 q1 = *reinterpret_cast<const float4*>(&M1s[1 * H_ + hb]);
      const float4 q2 = *reinterpret_cast<const float4*>(&M1s[2 * H_ + hb]);
      const float4 q3 = *reinterpret_cast<const float4*>(&M1s[3 * H_ + hb]);
      const float4 q4 = *reinterpret_cast<const float4*>(&M1s[4 * H_ + hb]);
      const float4 q5 = *reinterpret_cast<const float4*>(&M1s[5 * H_ + hb]);
      float4 a;
      a.x = fmaf(p2.y, q5.x, fmaf(p2.x, q4.x, fmaf(p1.y, q3.x, fmaf(p1.x, q2.x, fmaf(p0.y, q1.x, fmaf(p0.x, q0.x, c.x))))));
      a.y = fmaf(p2.y, q5.y, fmaf(p2.x, q4.y, fmaf(p1.y, q3.y, fmaf(p1.x, q2.y, fmaf(p0.y, q1.y, fmaf(p0.x, q0.y, c.y))))));
      a.z = fmaf(p2.y, q5.z, fmaf(p2.x, q4.z, fmaf(p1.y, q3.z, fmaf(p1.x, q2.z, fmaf(p0.y, q1.z, fmaf(p0.x, q0.z, c.z))))));
      a.w = fmaf(p2.y, q5.w, fmaf(p2.x, q4.w, fmaf(p1.y, q3.w, fmaf(p1.x, q2.w, fmaf(p0.y, q1.w, fmaf(p0.x, q0.w, c.w))))));
      float4 e;
      e.x = __expf(fminf(fmaxf(a.x, -60.f), 60.f));
      e.y = __expf(fminf(fmaxf(a.y, -60.f), 60.f));
      e.z = __expf(fminf(fmaxf(a.z, -60.f), 60.f));
      e.w = __expf(fminf(fmaxf(a.w, -60.f), 60.f));
      *reinterpret_cast<float4*>(etb + (P ^ (hq << 4))) = e;
    }
  }

  // ---- dec rows for both u's (pre-doubled weights, no a+a) ----
  {
    #pragma unroll
    for (int r = 0; r < 2; ++r) {
      const float* uv = user + ((size_t)b * U_ + (r ? uBc : uAc)) * 4;
      const float g0 = uv[0], g1 = uv[1], g2 = uv[2];
      #pragma unroll
      for (int hh = 0; hh < 2; ++hh) {
        const int h = lane + hh * 64;
        float a = c2s[h];
        a = fmaf(g0, M2s[0 * H_ + h], a);
        a = fmaf(g1, M2s[1 * H_ + h], a);
        a = fmaf(g2, M2s[2 * H_ + h], a);
        decs[w][r][h] = __expf(fminf(fmaxf(a, -60.f), 60.f));
      }
    }
  }
  __syncthreads();   // publish Et (decs same-wave, covered)

  if (uA >= U_) return;   // tail waves: no barriers remain, safe to exit

  // ---- survivor compaction: ballot ranks -> slist (row A ranks, then row B) ----
  unsigned long long W0[4], W1b[4];
  #pragma unroll
  for (int c = 0; c < 4; ++c) { W0[c] = __ballot(m[0][c] != 0); W1b[c] = __ballot(m[1][c] != 0); }
  const int kA = __popcll(W0[0]) + __popcll(W0[1]) + __popcll(W0[2]) + __popcll(W0[3]);
  const int kB = __popcll(W1b[0]) + __popcll(W1b[1]) + __popcll(W1b[2]) + __popcll(W1b[3]);
  const int K  = kA + kB;
  {
    const unsigned long long low = (1ull << lane) - 1ull;
    int rk = __popcll(W0[0] & low) + __popcll(W0[1] & low) + __popcll(W0[2] & low) + __popcll(W0[3] & low);
    #pragma unroll
    for (int c = 0; c < 4; ++c)
      if (m[0][c]) { slist[w][rk] = (unsigned char)(4 * lane + c); ++rk; }
    rk = kA + __popcll(W1b[0] & low) + __popcll(W1b[1] & low) + __popcll(W1b[2] & low) + __popcll(W1b[3] & low);
    #pragma unroll
    for (int c = 0; c < 4; ++c)
      if (m[1][c]) { slist[w][rk] = (unsigned char)(4 * lane + c); ++rk; }
  }

  // ---- slot metadata (static-indexed; slots are wave-uniformly active) ----
  int   sS[8], Pb[8], Db[8];
  float accT[8];
  #pragma unroll
  for (int t = 0; t < 8; ++t) {
    const int j   = lane + (t << 6);
    const int idx = (j < K) ? j : 0;
    const int sj  = slist[w][idx];
    sS[t]   = sj;
    Pb[t]   = (sj << 9) + ((sj & 7) << 4);                 // Et row base ^ swizzle
    Db[t]   = (w << 10) + ((j >= kA) ? 512 : 0);           // decs row byte base
    accT[t] = 0.f;
  }

  // ---- slot-major accumulation: acc_t = sum_h vt_h / (E[s_t][h]*D[row_t][h] + 1) ----
  {
    char* etb = (char*)Et;
    char* dcb = (char*)decs;
    #pragma unroll
    for (int t = 0; t < 8; ++t) {
      if ((t << 6) < K) {              // wave-uniform: slot has >=1 valid lane
        int p = Pb[t];
        int d = Db[t];
        float acc = 0.f;
        #pragma unroll 1
        for (int h8 = 0; h8 < 4; ++h8) {
          #pragma unroll
          for (int i = 0; i < 8; ++i) {
            const float4 e  = *reinterpret_cast<const float4*>(etb + (p ^ (i << 4)));
            const float4 dd = *reinterpret_cast<const float4*>(dcb + d + (i << 4));
            const float4 vv = *reinterpret_cast<const float4*>(vt + h8 * 32 + i * 4); // uniform -> scalar
            float t0 = fmaf(e.x, dd.x, 1.0f);
            float t1 = fmaf(e.y, dd.y, 1.0f);
            float t2 = fmaf(e.z, dd.z, 1.0f);
            float t3 = fmaf(e.w, dd.w, 1.0f);
            float t01 = t0 * t1;
            float t23 = t2 * t3;
            float n01 = fmaf(vv.x, t1, vv.y * t0);
            float n23 = fmaf(vv.z, t3, vv.w * t2);
            acc = fmaf(fmaf(n01, t23, n23 * t01), __builtin_amdgcn_rcpf(t01 * t23), acc);
          }
          p += 128; d += 128;
        }
        accT[t] = acc;
      }
    }
  }

  // ---- per-row softmax over slots + scatter survivors + fill masked ----
  const float negs = -103.6163291847321f * 10.0f;   // log(1e-45) * EXPLORATION_C
  const float vs10 = vsum_s * 10.0f;
  float sc[8];
  float mA = negs, mB = negs;
  #pragma unroll
  for (int t = 0; t < 8; ++t) {
    const int  j   = lane + (t << 6);
    const bool val = j < K;
    const bool isB = j >= kA;
    const float s  = val ? fmaf(-20.0f, accT[t], vs10) : negs;
    sc[t] = s;
    mA = fmaxf(mA, (val && !isB) ? s : negs);
    mB = fmaxf(mB, (val &&  isB) ? s : negs);
  }
  #pragma unroll
  for (int off = 32; off > 0; off >>= 1) {
    mA = fmaxf(mA, __shfl_xor(mA, off, 64));
    mB = fmaxf(mB, __shfl_xor(mB, off, 64));
  }
  float pv[8];
  float sA = 0.f, sB = 0.f;
  #pragma unroll
  for (int t = 0; t < 8; ++t) {
    const int  j   = lane + (t << 6);
    const bool val = j < K;
    const bool isB = j >= kA;
    const float p  = val ? __expf(sc[t] - (isB ? mB : mA)) : 0.f;
    pv[t] = p;
    sA += (val && !isB) ? p : 0.f;
    sB += (val &&  isB) ? p : 0.f;
  }
  #pragma unroll
  for (int off = 32; off > 0; off >>= 1) {
    sA += __shfl_xor(sA, off, 64);
    sB += __shfl_xor(sB, off, 64);
  }
  const float invA = __builtin_amdgcn_rcpf(sA);
  const float invB = __builtin_amdgcn_rcpf(sB);

  // survivors: owner-lane scatter (distinct addresses by construction)
  #pragma unroll
  for (int t = 0; t < 8; ++t) {
    const int j = lane + (t << 6);
    if (j < K) {
      const bool isB = j >= kA;
      out[(isB ? rowB : rowA) + sS[t]] = pv[t] * (isB ? invB : invA);
    }
  }
  // masked elements: 0 (underflow-exact vs reference), or 1/256 for all-masked rows
  const float fillA = kA ? 0.f : (1.0f / 256.0f);
  const float fillB = kB ? 0.f : (1.0f / 256.0f);
  #pragma unroll
  for (int c = 0; c < 4; ++c) {
    if (!m[0][c]) out[rowA + 4 * lane + c] = fillA;
    if (!m[1][c]) out[rowB + 4 * lane + c] = fillB;
  }
}

extern "C" void kernel_launch(void* const* d_in, const int* in_sizes, int n_in,
                              void* d_out, int out_size, void* d_ws, size_t ws_size,
                              hipStream_t stream) {
  const float* user   = (const float*)d_in[0];
  const float* server = (const float*)d_in[1];
  const int*   masks  = (const int*)d_in[2];
  const float* Wu = (const float*)d_in[3];
  const float* bu = (const float*)d_in[4];
  const float* Ws = (const float*)d_in[5];
  const float* bs = (const float*)d_in[6];
  const float* W1 = (const float*)d_in[7];
  const float* W2 = (const float*)d_in[8];
  const float* vt = (const float*)d_in[9];
  float* out = (float*)d_out;
  (void)in_sizes; (void)n_in; (void)out_size; (void)d_ws; (void)ws_size;

  attn_kernel<<<dim3(B_ * ((U_ + UTILE - 1) / UTILE)), dim3(TPB), 0, stream>>>(
      user, server, masks, Wu, bu, Ws, bs, W1, W2, vt, out);
}